// Round 2
// baseline (194.072 us; speedup 1.0000x reference)
//
#include <hip/hip_runtime.h>
#include <math.h>

#define NB 8
#define NS 1024
#define NV 32000

// ---------------------------------------------------------------------------
// Kernel 1: per-row logsumexp -> nll[row] = lse - logits[row, tgt[row]]
// One 256-thread block per (b,s) row. float4 coalesced loads.
// Fast path: UNCENTERED exp-sum (no online rescale -> no trans op in the
// serial accumulator chain; two independent accumulators for ILP).
// Safety: block-uniform fallback to centered two-pass if S over/underflows
// (never taken for sane logit magnitudes; row is L2-warm if it triggers).
// ---------------------------------------------------------------------------
__global__ __launch_bounds__(256)
void nll_kernel(const float* __restrict__ logits,
                const int* __restrict__ tgt,
                float* __restrict__ nll) {
    const int row = blockIdx.x;                 // 0 .. NB*NS-1
    const float* rp = logits + (size_t)row * NV;
    const int tid = threadIdx.x;
    const float4* rp4 = (const float4*)rp;
    const int n4 = NV / 4;                      // 8000

    float s0 = 0.f, s1 = 0.f;
    for (int i = tid; i < n4; i += 256) {
        float4 x = rp4[i];
        float e0 = __expf(x.x);
        float e1 = __expf(x.y);
        float e2 = __expf(x.z);
        float e3 = __expf(x.w);
        s0 += e0 + e1;                          // dep chain: 1 add per iter
        s1 += e2 + e3;
    }
    float s = s0 + s1;

    #pragma unroll
    for (int off = 1; off < 64; off <<= 1)
        s += __shfl_xor(s, off, 64);

    __shared__ float ssum[4];
    __shared__ float blk_s;
    const int wave = tid >> 6, lane = tid & 63;
    if (lane == 0) ssum[wave] = s;
    __syncthreads();
    if (tid == 0) blk_s = (ssum[0] + ssum[1]) + (ssum[2] + ssum[3]);
    __syncthreads();
    const float S = blk_s;

    if (S > 1.0e-30f && S < 3.0e38f) {          // fast path (block-uniform)
        if (tid == 0) nll[row] = __logf(S) - rp[tgt[row]];
        return;
    }

    // ---- fallback: max pass + centered pass (block-uniform, rare) ----
    float m = -INFINITY;
    for (int i = tid; i < n4; i += 256) {
        float4 x = rp4[i];
        m = fmaxf(m, fmaxf(fmaxf(x.x, x.y), fmaxf(x.z, x.w)));
    }
    #pragma unroll
    for (int off = 1; off < 64; off <<= 1)
        m = fmaxf(m, __shfl_xor(m, off, 64));
    __shared__ float smax[4];
    __shared__ float blk_m;
    if (lane == 0) smax[wave] = m;
    __syncthreads();
    if (tid == 0)
        blk_m = fmaxf(fmaxf(smax[0], smax[1]), fmaxf(smax[2], smax[3]));
    __syncthreads();
    const float M = blk_m;

    float c0 = 0.f, c1 = 0.f;
    for (int i = tid; i < n4; i += 256) {
        float4 x = rp4[i];
        c0 += __expf(x.x - M) + __expf(x.y - M);
        c1 += __expf(x.z - M) + __expf(x.w - M);
    }
    float c = c0 + c1;
    #pragma unroll
    for (int off = 1; off < 64; off <<= 1)
        c += __shfl_xor(c, off, 64);
    if (lane == 0) ssum[wave] = c;
    __syncthreads();
    if (tid == 0) {
        float S2 = (ssum[0] + ssum[1]) + (ssum[2] + ssum[3]);
        nll[row] = M + __logf(S2) - rp[tgt[row]];
    }
}

// ---------------------------------------------------------------------------
// Kernel 2 (fused reduce+finalize): one block, 512 threads.
// Wave b (of 8) reduces batch item b's category sums/counts via shuffles,
// then thread 0 computes the 4 scalar outputs exactly per the reference.
// ---------------------------------------------------------------------------
__global__ __launch_bounds__(512)
void reduce_finalize_kernel(const int* __restrict__ inp,
                            const float* __restrict__ nll,
                            float* __restrict__ out) {
    const int tid = threadIdx.x;
    const int b = tid >> 6;                     // wave index == batch item
    const int lane = tid & 63;
    const int base = b * NS;

    float acc[6] = {0.f, 0.f, 0.f, 0.f, 0.f, 0.f}; // {sum,cnt}x{reg,msk,spc}
    for (int i = lane; i < NS; i += 64) {
        int tok = inp[base + i];
        float v = nll[base + i];
        if (tok == 4)                { acc[2] += v; acc[3] += 1.f; }
        else if ((unsigned)tok < 4u) { acc[4] += v; acc[5] += 1.f; }
        else                         { acc[0] += v; acc[1] += 1.f; }
    }
    #pragma unroll
    for (int off = 1; off < 64; off <<= 1) {
        #pragma unroll
        for (int k = 0; k < 6; ++k) acc[k] += __shfl_xor(acc[k], off, 64);
    }

    __shared__ float part[NB][6];
    if (lane == 0) {
        #pragma unroll
        for (int k = 0; k < 6; ++k) part[b][k] = acc[k];
    }
    __syncthreads();

    if (tid == 0) {
        const float W[3] = {1.0f, 1.0f, 0.01f};
        float loss_acc = 0.f;
        float sum_m[3] = {0.f, 0.f, 0.f};
        float sum_p[3] = {0.f, 0.f, 0.f};
        for (int bb = 0; bb < NB; ++bb) {
            float num = 0.f, tw = 0.f;
            #pragma unroll
            for (int k = 0; k < 3; ++k) {
                float sv = part[bb][2 * k];
                float cn = part[bb][2 * k + 1];
                float p = (cn > 0.f) ? 1.f : 0.f;
                float mean = (cn > 0.f) ? (sv / cn) : 0.f;
                num += mean * W[k] * p;
                tw  += p * W[k];
                sum_m[k] += mean;
                sum_p[k] += p;
            }
            loss_acc += num / tw;
        }
        out[0] = loss_acc / (float)NB;
        #pragma unroll
        for (int k = 0; k < 3; ++k)
            out[1 + k] = (sum_p[k] > 0.f) ? (sum_m[k] / fmaxf(sum_p[k], 1.f))
                                          : 0.f;
    }
}

// ---------------------------------------------------------------------------
extern "C" void kernel_launch(void* const* d_in, const int* in_sizes, int n_in,
                              void* d_out, int out_size, void* d_ws, size_t ws_size,
                              hipStream_t stream) {
    const float* logits = (const float*)d_in[0];   // [B,S,V] f32
    const int*   inp    = (const int*)d_in[1];     // [B,S] i32
    const int*   tgt    = (const int*)d_in[2];     // [B,S] i32
    float* out = (float*)d_out;                    // 4 f32
    float* nll = (float*)d_ws;                     // B*S floats

    nll_kernel<<<NB * NS, 256, 0, stream>>>(logits, tgt, nll);
    reduce_finalize_kernel<<<1, 512, 0, stream>>>(inp, nll, out);
}